// Round 1
// baseline (300.291 us; speedup 1.0000x reference)
//
#include <hip/hip_runtime.h>

#define B_  32
#define CL_ 1024
#define QL_ 256
#define D_  768

typedef _Float16 f16x8 __attribute__((ext_vector_type(8)));
typedef float    f32x4 __attribute__((ext_vector_type(4)));

// ---------------- rowdot: out[row] = dot(X[row,:], w[:]) over D=768 ----------------
__global__ void rowdot_kernel(const float* __restrict__ X, const float* __restrict__ w,
                              float* __restrict__ out) {
    int wave = threadIdx.x >> 6;
    int lane = threadIdx.x & 63;
    int row  = blockIdx.x * 4 + wave;
    const float* x = X + (size_t)row * D_;
    float s = 0.f;
#pragma unroll
    for (int k = 0; k < D_ / 64; ++k) s += x[lane + k * 64] * w[lane + k * 64];
#pragma unroll
    for (int m = 32; m; m >>= 1) s += __shfl_xor(s, m, 64);
    if (lane == 0) out[row] = s;
}

// ---------------- transpose Q -> QT (f16), QT[b][d][j] ----------------
__global__ void transpose_q_kernel(const float* __restrict__ Q, _Float16* __restrict__ QT) {
    __shared__ float tile[32][33];
    int b  = blockIdx.z;
    int j0 = blockIdx.x * 32;
    int d0 = blockIdx.y * 32;
    int tx = threadIdx.x;
    for (int yy = threadIdx.y; yy < 32; yy += 8)
        tile[yy][tx] = Q[((size_t)b * QL_ + j0 + yy) * D_ + d0 + tx];
    __syncthreads();
    for (int yy = threadIdx.y; yy < 32; yy += 8)
        QT[((size_t)b * D_ + d0 + yy) * QL_ + j0 + tx] = (_Float16)tile[tx][yy];
}

// ---------------- S-GEMM: Sc[b,i,j] = clip(cw1[i]+qw2[j]+ (C[i]*w3)·Q[j]) ----------------
__global__ __launch_bounds__(256) void sgemm_kernel(
    const float* __restrict__ C, const float* __restrict__ Q, const float* __restrict__ w,
    const float* __restrict__ cw1, const float* __restrict__ qw2, float* __restrict__ Sc) {
    __shared__ __align__(16) _Float16 As[64 * 64];
    __shared__ __align__(16) _Float16 Bs[64 * 64];
    __shared__ float w3s[D_];
    int t  = threadIdx.x;
    int b  = blockIdx.z;
    int j0 = blockIdx.x * 64;
    int i0 = blockIdx.y * 64;
    for (int k = t; k < D_; k += 256) w3s[k] = w[2 * D_ + k];
    const float* Cbase = C + ((size_t)b * CL_ + i0) * D_;
    const float* Qbase = Q + ((size_t)b * QL_ + j0) * D_;
    int wave = t >> 6, lane = t & 63, lrow = lane & 15, lk = lane >> 4;
    f32x4 acc[4] = {};
    for (int k0 = 0; k0 < D_; k0 += 64) {
        __syncthreads();
#pragma unroll
        for (int s2 = 0; s2 < 2; ++s2) {
            int slot = t * 2 + s2;
            int row = slot >> 3, sc = slot & 7;
            int kk0 = k0 + sc * 8;
            float4 a0 = *(const float4*)(Cbase + (size_t)row * D_ + kk0);
            float4 a1 = *(const float4*)(Cbase + (size_t)row * D_ + kk0 + 4);
            float4 b0 = *(const float4*)(Qbase + (size_t)row * D_ + kk0);
            float4 b1 = *(const float4*)(Qbase + (size_t)row * D_ + kk0 + 4);
            float4 w0 = *(const float4*)(&w3s[kk0]);
            float4 w1 = *(const float4*)(&w3s[kk0 + 4]);
            f16x8 ah, bh;
            ah[0] = (_Float16)(a0.x * w0.x); ah[1] = (_Float16)(a0.y * w0.y);
            ah[2] = (_Float16)(a0.z * w0.z); ah[3] = (_Float16)(a0.w * w0.w);
            ah[4] = (_Float16)(a1.x * w1.x); ah[5] = (_Float16)(a1.y * w1.y);
            ah[6] = (_Float16)(a1.z * w1.z); ah[7] = (_Float16)(a1.w * w1.w);
            bh[0] = (_Float16)b0.x; bh[1] = (_Float16)b0.y;
            bh[2] = (_Float16)b0.z; bh[3] = (_Float16)b0.w;
            bh[4] = (_Float16)b1.x; bh[5] = (_Float16)b1.y;
            bh[6] = (_Float16)b1.z; bh[7] = (_Float16)b1.w;
            int sw = sc ^ (row & 7);
            *(f16x8*)&As[row * 64 + sw * 8] = ah;
            *(f16x8*)&Bs[row * 64 + sw * 8] = bh;
        }
        __syncthreads();
#pragma unroll
        for (int kk = 0; kk < 2; ++kk) {
            int slot = kk * 4 + lk;
            int ra = wave * 16 + lrow;
            f16x8 af = *(const f16x8*)&As[ra * 64 + ((slot ^ (ra & 7)) * 8)];
#pragma unroll
            for (int n = 0; n < 4; ++n) {
                int rb = n * 16 + lrow;
                f16x8 bf = *(const f16x8*)&Bs[rb * 64 + ((slot ^ (rb & 7)) * 8)];
                acc[n] = __builtin_amdgcn_mfma_f32_16x16x32_f16(af, bf, acc[n], 0, 0, 0);
            }
        }
    }
    float cw[4];
#pragma unroll
    for (int r = 0; r < 4; ++r) cw[r] = cw1[(size_t)b * CL_ + i0 + wave * 16 + lk * 4 + r];
#pragma unroll
    for (int n = 0; n < 4; ++n) {
        int j = j0 + n * 16 + lrow;
        float qv = qw2[(size_t)b * QL_ + j];
#pragma unroll
        for (int r = 0; r < 4; ++r) {
            int i = i0 + wave * 16 + lk * 4 + r;
            float v = acc[n][r] + cw[r] + qv;
            v = fminf(15.f, fmaxf(-15.f, v));
            Sc[((size_t)b * CL_ + i) * QL_ + j] = v;
        }
    }
}

// ---------------- row softmax (axis=j, q_mask), S1 as f16 ----------------
__global__ void softmax_rows_kernel(const float* __restrict__ Sc, const int* __restrict__ q_mask,
                                    _Float16* __restrict__ S1h) {
    int wave = threadIdx.x >> 6, lane = threadIdx.x & 63;
    int row = blockIdx.x * 4 + wave;          // row in [0, B*CL)
    int b = row >> 10;                        // CL = 1024
    const float* src = Sc + (size_t)row * QL_;
    const int* qm = q_mask + b * QL_;
    float v[4]; int msk[4];
    float mx = -1e30f;
#pragma unroll
    for (int e = 0; e < 4; ++e) {
        int j = lane + 64 * e;
        v[e] = src[j];
        msk[e] = qm[j];
        float x = msk[e] ? v[e] : 0.0f;
        mx = fmaxf(mx, x);
    }
#pragma unroll
    for (int m = 32; m; m >>= 1) mx = fmaxf(mx, __shfl_xor(mx, m, 64));
    float ev[4], s = 0.f;
#pragma unroll
    for (int e = 0; e < 4; ++e) {
        ev[e] = msk[e] ? expf(v[e] - mx) : 0.0f;
        s += ev[e];
    }
#pragma unroll
    for (int m = 32; m; m >>= 1) s += __shfl_xor(s, m, 64);
    float inv = 1.0f / (s + 1e-6f);
#pragma unroll
    for (int e = 0; e < 4; ++e)
        S1h[(size_t)row * QL_ + lane + 64 * e] = (_Float16)(ev[e] * inv);
}

// ---------------- column online stats (partial over 128-row slices) ----------------
__global__ void col_part_kernel(const float* __restrict__ Sc, const int* __restrict__ c_mask,
                                float* __restrict__ pm, float* __restrict__ ps,
                                float* __restrict__ pum) {
    int b = blockIdx.x, slice = blockIdx.y;
    int j = threadIdx.x;
    float m = -1e30f, s = 0.f, um = -1e30f;
    const float* base = Sc + ((size_t)b * CL_ + slice * 128) * QL_ + j;
    const int* cm = c_mask + b * CL_ + slice * 128;
    for (int ii = 0; ii < 128; ++ii) {
        float v = base[(size_t)ii * QL_];
        int cmv = cm[ii];
        float x = cmv ? v : 0.0f;
        if (x > m) { s *= expf(m - x); m = x; }
        if (cmv) { s += expf(v - m); um = fmaxf(um, v); }
    }
    int idx = (b * 8 + slice) * QL_ + j;
    pm[idx] = m; ps[idx] = s; pum[idx] = um;
}

__global__ void col_combine_kernel(const float* __restrict__ pm, const float* __restrict__ ps,
                                   const float* __restrict__ pum, float* __restrict__ s2max) {
    int b = blockIdx.x;
    int j = threadIdx.x;
    float m = -1e30f, s = 0.f, um = -1e30f;
    for (int k = 0; k < 8; ++k) {
        int idx = (b * 8 + k) * QL_ + j;
        float mk = pm[idx], sk = ps[idx], umk = pum[idx];
        float nm = fmaxf(m, mk);
        s = s * expf(m - nm) + sk * expf(mk - nm);
        m = nm;
        um = fmaxf(um, umk);
    }
    float r = (um < -1e29f) ? 0.0f : expf(um - m) / (s + 1e-6f);
    s2max[b * QL_ + j] = r;
}

// ---------------- Bmat[b,d] = sum_j s2max[b,j] * Q[b,j,d] ----------------
__global__ void bmat_kernel(const float* __restrict__ s2max, const float* __restrict__ Q,
                            float* __restrict__ bmat) {
    int b = blockIdx.x;
    int d = blockIdx.y * 256 + threadIdx.x;
    const float* qb = Q + (size_t)b * QL_ * D_ + d;
    const float* sm = s2max + b * QL_;
    float s = 0.f;
    for (int j = 0; j < QL_; ++j) s += sm[j] * qb[(size_t)j * D_];
    bmat[b * D_ + d] = s;
}

// ---------------- A-GEMM (S1 @ Q) with fused 4-segment output epilogue ----------------
__global__ __launch_bounds__(256) void agemm_out_kernel(
    const _Float16* __restrict__ S1h, const _Float16* __restrict__ QTh,
    const float* __restrict__ C, const float* __restrict__ bmat, float* __restrict__ out) {
    __shared__ __align__(16) _Float16 As[64 * 64];
    __shared__ __align__(16) _Float16 Bs[64 * 64];
    int t  = threadIdx.x;
    int b  = blockIdx.z;
    int d0 = blockIdx.x * 64;
    int i0 = blockIdx.y * 64;
    const _Float16* Sbase = S1h + ((size_t)b * CL_ + i0) * QL_;
    const _Float16* Qbase = QTh + ((size_t)b * D_ + d0) * QL_;
    int wave = t >> 6, lane = t & 63, lrow = lane & 15, lk = lane >> 4;
    f32x4 acc[4] = {};
    for (int k0 = 0; k0 < QL_; k0 += 64) {
        __syncthreads();
#pragma unroll
        for (int s2 = 0; s2 < 2; ++s2) {
            int slot = t * 2 + s2;
            int row = slot >> 3, sc = slot & 7;
            f16x8 av = *(const f16x8*)(Sbase + (size_t)row * QL_ + k0 + sc * 8);
            f16x8 bv = *(const f16x8*)(Qbase + (size_t)row * QL_ + k0 + sc * 8);
            int sw = sc ^ (row & 7);
            *(f16x8*)&As[row * 64 + sw * 8] = av;
            *(f16x8*)&Bs[row * 64 + sw * 8] = bv;
        }
        __syncthreads();
#pragma unroll
        for (int kk = 0; kk < 2; ++kk) {
            int slot = kk * 4 + lk;
            int ra = wave * 16 + lrow;
            f16x8 af = *(const f16x8*)&As[ra * 64 + ((slot ^ (ra & 7)) * 8)];
#pragma unroll
            for (int n = 0; n < 4; ++n) {
                int rb = n * 16 + lrow;
                f16x8 bf = *(const f16x8*)&Bs[rb * 64 + ((slot ^ (rb & 7)) * 8)];
                acc[n] = __builtin_amdgcn_mfma_f32_16x16x32_f16(af, bf, acc[n], 0, 0, 0);
            }
        }
    }
#pragma unroll
    for (int n = 0; n < 4; ++n) {
        int d = d0 + n * 16 + lrow;
        float bm = bmat[b * D_ + d];
#pragma unroll
        for (int r = 0; r < 4; ++r) {
            int i = i0 + wave * 16 + lk * 4 + r;
            float a = acc[n][r];
            float c = C[((size_t)b * CL_ + i) * D_ + d];
            size_t ob = ((size_t)b * CL_ + i) * (size_t)(4 * D_);
            out[ob + d]            = c;
            out[ob + D_ + d]       = a;
            out[ob + 2 * D_ + d]   = c * a;
            out[ob + 3 * D_ + d]   = c * bm;
        }
    }
}

extern "C" void kernel_launch(void* const* d_in, const int* in_sizes, int n_in,
                              void* d_out, int out_size, void* d_ws, size_t ws_size,
                              hipStream_t stream) {
    const float* C      = (const float*)d_in[0];
    const float* Q      = (const float*)d_in[1];
    const float* w      = (const float*)d_in[2];
    const int*   c_mask = (const int*)d_in[3];
    const int*   q_mask = (const int*)d_in[4];
    float* out = (float*)d_out;
    char* ws = (char*)d_ws;

    // workspace layout (bytes)
    float*    Sc    = (float*)(ws);                         // 33,554,432
    _Float16* S1h   = (_Float16*)(ws + 33554432);           // 16,777,216
    _Float16* QTh   = (_Float16*)(ws + 50331648);           // 12,582,912
    float*    cw1   = (float*)(ws + 62914560);              //    131,072
    float*    qw2   = (float*)(ws + 63045632);              //     32,768
    float*    pm    = (float*)(ws + 63078400);              //    262,144
    float*    ps    = (float*)(ws + 63340544);              //    262,144
    float*    pum   = (float*)(ws + 63602688);              //    262,144
    float*    s2max = (float*)(ws + 63864832);              //     32,768
    float*    bmat  = (float*)(ws + 63897600);              //     98,304

    rowdot_kernel<<<dim3((B_ * CL_) / 4), 256, 0, stream>>>(C, w, cw1);
    rowdot_kernel<<<dim3((B_ * QL_) / 4), 256, 0, stream>>>(Q, w + D_, qw2);
    transpose_q_kernel<<<dim3(QL_ / 32, D_ / 32, B_), dim3(32, 8), 0, stream>>>(Q, QTh);
    sgemm_kernel<<<dim3(QL_ / 64, CL_ / 64, B_), 256, 0, stream>>>(C, Q, w, cw1, qw2, Sc);
    softmax_rows_kernel<<<dim3((B_ * CL_) / 4), 256, 0, stream>>>(Sc, q_mask, S1h);
    col_part_kernel<<<dim3(B_, 8), 256, 0, stream>>>(Sc, c_mask, pm, ps, pum);
    col_combine_kernel<<<dim3(B_), 256, 0, stream>>>(pm, ps, pum, s2max);
    bmat_kernel<<<dim3(B_, D_ / 256), 256, 0, stream>>>(s2max, Q, bmat);
    agemm_out_kernel<<<dim3(D_ / 64, CL_ / 64, B_), 256, 0, stream>>>(S1h, QTh, C, bmat, out);
}

// Round 2
// 233.189 us; speedup vs baseline: 1.2878x; 1.2878x over previous
//
#include <hip/hip_runtime.h>

#define B_  32
#define CL_ 1024
#define QL_ 256
#define D_  768

typedef _Float16 f16x8 __attribute__((ext_vector_type(8)));
typedef float    f32x4 __attribute__((ext_vector_type(4)));

// ---------------- rowdot: out[row] = dot(X[row,:], w[:]) over D=768 ----------------
__global__ void rowdot_kernel(const float* __restrict__ X, const float* __restrict__ w,
                              float* __restrict__ out) {
    int wave = threadIdx.x >> 6;
    int lane = threadIdx.x & 63;
    int row  = blockIdx.x * 4 + wave;
    const float* x = X + (size_t)row * D_;
    float s = 0.f;
#pragma unroll
    for (int k = 0; k < D_ / 64; ++k) s += x[lane + k * 64] * w[lane + k * 64];
#pragma unroll
    for (int m = 32; m; m >>= 1) s += __shfl_xor(s, m, 64);
    if (lane == 0) out[row] = s;
}

// ---------------- prep Q: QT[b][d][j] f16  and  Qh[b][j][d] f16 ----------------
__global__ void prep_q_kernel(const float* __restrict__ Q, _Float16* __restrict__ QT,
                              _Float16* __restrict__ Qh) {
    __shared__ float tile[32][33];
    int b  = blockIdx.z;
    int j0 = blockIdx.x * 32;
    int d0 = blockIdx.y * 32;
    int tx = threadIdx.x;
    for (int yy = threadIdx.y; yy < 32; yy += 8) {
        float v = Q[((size_t)b * QL_ + j0 + yy) * D_ + d0 + tx];
        tile[yy][tx] = v;
        Qh[((size_t)b * QL_ + j0 + yy) * D_ + d0 + tx] = (_Float16)v;
    }
    __syncthreads();
    for (int yy = threadIdx.y; yy < 32; yy += 8)
        QT[((size_t)b * D_ + d0 + yy) * QL_ + j0 + tx] = (_Float16)tile[tx][yy];
}

// ---------------- fused: S-GEMM (64 x 256) + cw1 + row softmax -> S1h + col partial stats ----
__global__ __launch_bounds__(256, 2) void fused_s_kernel(
    const float* __restrict__ C, const _Float16* __restrict__ Qh,
    const float* __restrict__ w, const float* __restrict__ qw2g,
    const int* __restrict__ c_mask, const int* __restrict__ q_mask,
    _Float16* __restrict__ S1h, float* __restrict__ pmg,
    float* __restrict__ psg, float* __restrict__ pumg) {
    __shared__ __align__(16) _Float16 As[64 * 64];
    __shared__ __align__(16) _Float16 Bs[256 * 64];
    __shared__ float w1s[D_], w3s[D_];
    __shared__ float cw1s[64];
    __shared__ float rowredM[256], rowredS[256];
    __shared__ int   cms[64], qms[256];

    int t = threadIdx.x;
    int slice = blockIdx.x;      // 0..15
    int b = blockIdx.y;
    int i0 = slice * 64;
    int wave = t >> 6, lane = t & 63, lrow = lane & 15, lk = lane >> 4;
    int jw = wave * 64;

    for (int k = t; k < D_; k += 256) { w1s[k] = w[k]; w3s[k] = w[2 * D_ + k]; }
    if (t < 64) cms[t] = c_mask[b * CL_ + i0 + t];
    qms[t] = q_mask[b * QL_ + t];

    const float* Cbase = C + ((size_t)b * CL_ + i0) * D_;
    const _Float16* Qbase = Qh + (size_t)b * QL_ * D_;

    f32x4 acc[4][4] = {};
    float cwp0 = 0.f, cwp1 = 0.f;
    int arow0 = t >> 3, arow1 = 32 + (t >> 3);
    int asc = t & 7;

    for (int k0 = 0; k0 < D_; k0 += 64) {
        __syncthreads();
        {
            int kk0 = k0 + asc * 8;
            float4 w30 = *(const float4*)(&w3s[kk0]);
            float4 w31 = *(const float4*)(&w3s[kk0 + 4]);
            float4 w10 = *(const float4*)(&w1s[kk0]);
            float4 w11 = *(const float4*)(&w1s[kk0 + 4]);
            const float* src0 = Cbase + (size_t)arow0 * D_ + kk0;
            float4 a0 = *(const float4*)src0;
            float4 a1 = *(const float4*)(src0 + 4);
            f16x8 ah;
            ah[0] = (_Float16)(a0.x * w30.x); ah[1] = (_Float16)(a0.y * w30.y);
            ah[2] = (_Float16)(a0.z * w30.z); ah[3] = (_Float16)(a0.w * w30.w);
            ah[4] = (_Float16)(a1.x * w31.x); ah[5] = (_Float16)(a1.y * w31.y);
            ah[6] = (_Float16)(a1.z * w31.z); ah[7] = (_Float16)(a1.w * w31.w);
            cwp0 += a0.x * w10.x + a0.y * w10.y + a0.z * w10.z + a0.w * w10.w
                  + a1.x * w11.x + a1.y * w11.y + a1.z * w11.z + a1.w * w11.w;
            *(f16x8*)&As[arow0 * 64 + ((asc ^ (arow0 & 7)) * 8)] = ah;
            const float* src1 = Cbase + (size_t)arow1 * D_ + kk0;
            float4 b0 = *(const float4*)src1;
            float4 b1 = *(const float4*)(src1 + 4);
            f16x8 bh;
            bh[0] = (_Float16)(b0.x * w30.x); bh[1] = (_Float16)(b0.y * w30.y);
            bh[2] = (_Float16)(b0.z * w30.z); bh[3] = (_Float16)(b0.w * w30.w);
            bh[4] = (_Float16)(b1.x * w31.x); bh[5] = (_Float16)(b1.y * w31.y);
            bh[6] = (_Float16)(b1.z * w31.z); bh[7] = (_Float16)(b1.w * w31.w);
            cwp1 += b0.x * w10.x + b0.y * w10.y + b0.z * w10.z + b0.w * w10.w
                  + b1.x * w11.x + b1.y * w11.y + b1.z * w11.z + b1.w * w11.w;
            *(f16x8*)&As[arow1 * 64 + ((asc ^ (arow1 & 7)) * 8)] = bh;
        }
#pragma unroll
        for (int sb = 0; sb < 8; ++sb) {
            int row = sb * 32 + (t >> 3);
            f16x8 bh = *(const f16x8*)(Qbase + (size_t)row * D_ + k0 + asc * 8);
            *(f16x8*)&Bs[row * 64 + ((asc ^ (row & 7)) * 8)] = bh;
        }
        __syncthreads();
#pragma unroll
        for (int kk = 0; kk < 2; ++kk) {
            int slot = kk * 4 + lk;
            int swa = (slot ^ (lrow & 7)) * 8;
            f16x8 af[4];
#pragma unroll
            for (int m = 0; m < 4; ++m) af[m] = *(const f16x8*)&As[(m * 16 + lrow) * 64 + swa];
#pragma unroll
            for (int n = 0; n < 4; ++n) {
                int rb = jw + n * 16 + lrow;
                f16x8 bf = *(const f16x8*)&Bs[rb * 64 + swa];
#pragma unroll
                for (int m = 0; m < 4; ++m)
                    acc[m][n] = __builtin_amdgcn_mfma_f32_16x16x32_f16(af[m], bf, acc[m][n], 0, 0, 0);
            }
        }
    }

    // ---- cw1 reduction: 8 threads (t&7) share each row ----
    cwp0 += __shfl_xor(cwp0, 1, 64); cwp0 += __shfl_xor(cwp0, 2, 64); cwp0 += __shfl_xor(cwp0, 4, 64);
    cwp1 += __shfl_xor(cwp1, 1, 64); cwp1 += __shfl_xor(cwp1, 2, 64); cwp1 += __shfl_xor(cwp1, 4, 64);
    if ((t & 7) == 0) { cw1s[arow0] = cwp0; cw1s[arow1] = cwp1; }
    __syncthreads();

    // ---- S = clip(acc + cw1 + qw2) in-register ----
    float qwv[4]; int qmv[4];
#pragma unroll
    for (int n = 0; n < 4; ++n) {
        int j = jw + n * 16 + lrow;
        qwv[n] = qw2g[b * QL_ + j];
        qmv[n] = qms[j];
    }
#pragma unroll
    for (int m = 0; m < 4; ++m) {
#pragma unroll
        for (int r = 0; r < 4; ++r) {
            float cw = cw1s[m * 16 + lk * 4 + r];
#pragma unroll
            for (int n = 0; n < 4; ++n) {
                float v = acc[m][n][r] + cw + qwv[n];
                acc[m][n][r] = fminf(15.f, fmaxf(-15.f, v));
            }
        }
    }

    // ---- column partial stats (per j over this 64-row slice) ----
    {
        float pmv[4], psv[4], pumv[4];
#pragma unroll
        for (int n = 0; n < 4; ++n) {
            float pmax = -1e30f, umax = -1e30f;
#pragma unroll
            for (int m = 0; m < 4; ++m)
#pragma unroll
                for (int r = 0; r < 4; ++r) {
                    int cm = cms[m * 16 + lk * 4 + r];
                    float v = acc[m][n][r];
                    pmax = fmaxf(pmax, cm ? v : 0.0f);
                    umax = fmaxf(umax, cm ? v : -1e30f);
                }
            float s = 0.f;
#pragma unroll
            for (int m = 0; m < 4; ++m)
#pragma unroll
                for (int r = 0; r < 4; ++r) {
                    int cm = cms[m * 16 + lk * 4 + r];
                    s += cm ? __expf(acc[m][n][r] - pmax) : 0.0f;
                }
            pmv[n] = pmax; psv[n] = s; pumv[n] = umax;
        }
#pragma unroll
        for (int off = 16; off <= 32; off <<= 1) {
#pragma unroll
            for (int n = 0; n < 4; ++n) {
                float om = __shfl_xor(pmv[n], off, 64);
                float os = __shfl_xor(psv[n], off, 64);
                float ou = __shfl_xor(pumv[n], off, 64);
                float nm = fmaxf(pmv[n], om);
                psv[n] = psv[n] * __expf(pmv[n] - nm) + os * __expf(om - nm);
                pmv[n] = nm;
                pumv[n] = fmaxf(pumv[n], ou);
            }
        }
        if (lk == 0) {
#pragma unroll
            for (int n = 0; n < 4; ++n) {
                int idx = (b * 16 + slice) * QL_ + jw + n * 16 + lrow;
                pmg[idx] = pmv[n]; psg[idx] = psv[n]; pumg[idx] = pumv[n];
            }
        }
    }

    // ---- row softmax (masked by q_mask), cross-wave combine ----
    float Mv[4][4];
#pragma unroll
    for (int m = 0; m < 4; ++m)
#pragma unroll
        for (int r = 0; r < 4; ++r) {
            float lm = qmv[0] ? acc[m][0][r] : 0.0f;
#pragma unroll
            for (int n = 1; n < 4; ++n) lm = fmaxf(lm, qmv[n] ? acc[m][n][r] : 0.0f);
            lm = fmaxf(lm, __shfl_xor(lm, 1, 64));
            lm = fmaxf(lm, __shfl_xor(lm, 2, 64));
            lm = fmaxf(lm, __shfl_xor(lm, 4, 64));
            lm = fmaxf(lm, __shfl_xor(lm, 8, 64));
            Mv[m][r] = lm;
        }
    if (lrow == 0) {
#pragma unroll
        for (int m = 0; m < 4; ++m)
#pragma unroll
            for (int r = 0; r < 4; ++r)
                rowredM[wave * 64 + m * 16 + lk * 4 + r] = Mv[m][r];
    }
    __syncthreads();
#pragma unroll
    for (int m = 0; m < 4; ++m)
#pragma unroll
        for (int r = 0; r < 4; ++r) {
            int row = m * 16 + lk * 4 + r;
            Mv[m][r] = fmaxf(fmaxf(rowredM[row], rowredM[64 + row]),
                             fmaxf(rowredM[128 + row], rowredM[192 + row]));
        }
    float inv_[4][4];
#pragma unroll
    for (int m = 0; m < 4; ++m)
#pragma unroll
        for (int r = 0; r < 4; ++r) {
            float ls = 0.f;
#pragma unroll
            for (int n = 0; n < 4; ++n) {
                float e = qmv[n] ? __expf(acc[m][n][r] - Mv[m][r]) : 0.0f;
                acc[m][n][r] = e;
                ls += e;
            }
            ls += __shfl_xor(ls, 1, 64);
            ls += __shfl_xor(ls, 2, 64);
            ls += __shfl_xor(ls, 4, 64);
            ls += __shfl_xor(ls, 8, 64);
            if (lrow == 0) rowredS[wave * 64 + m * 16 + lk * 4 + r] = ls;
        }
    __syncthreads();
#pragma unroll
    for (int m = 0; m < 4; ++m)
#pragma unroll
        for (int r = 0; r < 4; ++r) {
            int row = m * 16 + lk * 4 + r;
            float sum = rowredS[row] + rowredS[64 + row] + rowredS[128 + row] + rowredS[192 + row];
            inv_[m][r] = 1.0f / (sum + 1e-6f);
        }

    // ---- write S1 (f16) via swizzled LDS (reuse Bs), then coalesced global writeback ----
    char* Bs2 = (char*)Bs;
#pragma unroll
    for (int m = 0; m < 4; ++m)
#pragma unroll
        for (int n = 0; n < 4; ++n)
#pragma unroll
            for (int r = 0; r < 4; ++r) {
                int il = m * 16 + lk * 4 + r;
                int j = jw + n * 16 + lrow;
                int byte = il * 512 + (((j >> 3) ^ (il & 7)) * 16) + (j & 7) * 2;
                *(_Float16*)(Bs2 + byte) = (_Float16)(acc[m][n][r] * inv_[m][r]);
            }
    __syncthreads();
#pragma unroll
    for (int sb = 0; sb < 8; ++sb) {
        int row = sb * 8 + (t >> 5);
        int c = t & 31;
        uint4 v = *(uint4*)(Bs2 + row * 512 + ((c ^ (row & 7)) * 16));
        *(uint4*)(S1h + ((size_t)(b * CL_ + i0 + row)) * QL_ + c * 8) = v;
    }
}

// ---------------- column combine over 16 slices -> s2max ----------------
__global__ void col_combine_kernel(const float* __restrict__ pm, const float* __restrict__ ps,
                                   const float* __restrict__ pum, float* __restrict__ s2max) {
    int b = blockIdx.x;
    int j = threadIdx.x;
    float m = -1e30f, s = 0.f, um = -1e30f;
    for (int k = 0; k < 16; ++k) {
        int idx = (b * 16 + k) * QL_ + j;
        float mk = pm[idx], sk = ps[idx], umk = pum[idx];
        float nm = fmaxf(m, mk);
        s = s * __expf(m - nm) + sk * __expf(mk - nm);
        m = nm;
        um = fmaxf(um, umk);
    }
    float r = (um < -1e29f) ? 0.0f : __expf(um - m) / (s + 1e-6f);
    s2max[b * QL_ + j] = r;
}

// ---------------- Bmat[b,d] = sum_j s2max[b,j] * Q[b,j,d] ----------------
__global__ void bmat_kernel(const float* __restrict__ s2max, const float* __restrict__ Q,
                            float* __restrict__ bmat) {
    int b = blockIdx.x;
    int d = blockIdx.y * 256 + threadIdx.x;
    const float* qb = Q + (size_t)b * QL_ * D_ + d;
    const float* sm = s2max + b * QL_;
    float s = 0.f;
    for (int j = 0; j < QL_; ++j) s += sm[j] * qb[(size_t)j * D_];
    bmat[b * D_ + d] = s;
}

// ---------------- A-GEMM (S1 @ Q) with fused 4-segment output epilogue ----------------
__global__ __launch_bounds__(256) void agemm_out_kernel(
    const _Float16* __restrict__ S1h, const _Float16* __restrict__ QTh,
    const float* __restrict__ C, const float* __restrict__ bmat, float* __restrict__ out) {
    __shared__ __align__(16) _Float16 As[64 * 64];
    __shared__ __align__(16) _Float16 Bs[64 * 64];
    int t  = threadIdx.x;
    int b  = blockIdx.z;
    int d0 = blockIdx.x * 64;
    int i0 = blockIdx.y * 64;
    const _Float16* Sbase = S1h + ((size_t)b * CL_ + i0) * QL_;
    const _Float16* Qbase = QTh + ((size_t)b * D_ + d0) * QL_;
    int wave = t >> 6, lane = t & 63, lrow = lane & 15, lk = lane >> 4;
    f32x4 acc[4] = {};
    for (int k0 = 0; k0 < QL_; k0 += 64) {
        __syncthreads();
#pragma unroll
        for (int s2 = 0; s2 < 2; ++s2) {
            int slot = t * 2 + s2;
            int row = slot >> 3, sc = slot & 7;
            f16x8 av = *(const f16x8*)(Sbase + (size_t)row * QL_ + k0 + sc * 8);
            f16x8 bv = *(const f16x8*)(Qbase + (size_t)row * QL_ + k0 + sc * 8);
            int sw = sc ^ (row & 7);
            *(f16x8*)&As[row * 64 + sw * 8] = av;
            *(f16x8*)&Bs[row * 64 + sw * 8] = bv;
        }
        __syncthreads();
#pragma unroll
        for (int kk = 0; kk < 2; ++kk) {
            int slot = kk * 4 + lk;
            int ra = wave * 16 + lrow;
            f16x8 af = *(const f16x8*)&As[ra * 64 + ((slot ^ (ra & 7)) * 8)];
#pragma unroll
            for (int n = 0; n < 4; ++n) {
                int rb = n * 16 + lrow;
                f16x8 bf = *(const f16x8*)&Bs[rb * 64 + ((slot ^ (rb & 7)) * 8)];
                acc[n] = __builtin_amdgcn_mfma_f32_16x16x32_f16(af, bf, acc[n], 0, 0, 0);
            }
        }
    }
#pragma unroll
    for (int n = 0; n < 4; ++n) {
        int d = d0 + n * 16 + lrow;
        float bm = bmat[b * D_ + d];
#pragma unroll
        for (int r = 0; r < 4; ++r) {
            int i = i0 + wave * 16 + lk * 4 + r;
            float a = acc[n][r];
            float c = C[((size_t)b * CL_ + i) * D_ + d];
            size_t ob = ((size_t)b * CL_ + i) * (size_t)(4 * D_);
            __builtin_nontemporal_store(c,      &out[ob + d]);
            __builtin_nontemporal_store(a,      &out[ob + D_ + d]);
            __builtin_nontemporal_store(c * a,  &out[ob + 2 * D_ + d]);
            __builtin_nontemporal_store(c * bm, &out[ob + 3 * D_ + d]);
        }
    }
}

extern "C" void kernel_launch(void* const* d_in, const int* in_sizes, int n_in,
                              void* d_out, int out_size, void* d_ws, size_t ws_size,
                              hipStream_t stream) {
    const float* C      = (const float*)d_in[0];
    const float* Q      = (const float*)d_in[1];
    const float* w      = (const float*)d_in[2];
    const int*   c_mask = (const int*)d_in[3];
    const int*   q_mask = (const int*)d_in[4];
    float* out = (float*)d_out;
    char* ws = (char*)d_ws;

    // workspace layout (bytes)
    _Float16* S1h   = (_Float16*)(ws);                      // 16,777,216
    _Float16* QTh   = (_Float16*)(ws + 16777216);           // 12,582,912
    _Float16* Qh    = (_Float16*)(ws + 29360128);           // 12,582,912
    float*    qw2   = (float*)(ws + 41943040);              //     32,768
    float*    pm    = (float*)(ws + 41975808);              //    524,288
    float*    ps    = (float*)(ws + 42500096);              //    524,288
    float*    pum   = (float*)(ws + 43024384);              //    524,288
    float*    s2max = (float*)(ws + 43548672);              //     32,768
    float*    bmat  = (float*)(ws + 43581440);              //     98,304

    rowdot_kernel<<<dim3((B_ * QL_) / 4), 256, 0, stream>>>(Q, w + D_, qw2);
    prep_q_kernel<<<dim3(QL_ / 32, D_ / 32, B_), dim3(32, 8), 0, stream>>>(Q, QTh, Qh);
    fused_s_kernel<<<dim3(CL_ / 64, B_), 256, 0, stream>>>(C, Qh, w, qw2, c_mask, q_mask,
                                                           S1h, pm, ps, pum);
    col_combine_kernel<<<dim3(B_), 256, 0, stream>>>(pm, ps, pum, s2max);
    bmat_kernel<<<dim3(B_, D_ / 256), 256, 0, stream>>>(s2max, Q, bmat);
    agemm_out_kernel<<<dim3(D_ / 64, CL_ / 64, B_), 256, 0, stream>>>(S1h, QTh, C, bmat, out);
}

// Round 3
// 221.209 us; speedup vs baseline: 1.3575x; 1.0542x over previous
//
#include <hip/hip_runtime.h>

#define B_  32
#define CL_ 1024
#define QL_ 256
#define D_  768

typedef _Float16 f16x8 __attribute__((ext_vector_type(8)));
typedef float    f32x4 __attribute__((ext_vector_type(4)));

// ---------------- rowdot: out[row] = dot(X[row,:], w[:]) over D=768 ----------------
__global__ void rowdot_kernel(const float* __restrict__ X, const float* __restrict__ w,
                              float* __restrict__ out) {
    int wave = threadIdx.x >> 6;
    int lane = threadIdx.x & 63;
    int row  = blockIdx.x * 4 + wave;
    const float* x = X + (size_t)row * D_;
    float s = 0.f;
#pragma unroll
    for (int k = 0; k < D_ / 64; ++k) s += x[lane + k * 64] * w[lane + k * 64];
#pragma unroll
    for (int m = 32; m; m >>= 1) s += __shfl_xor(s, m, 64);
    if (lane == 0) out[row] = s;
}

// ---------------- prep Q: QT[b][d][j] f16  and  Qh[b][j][d] f16 ----------------
__global__ void prep_q_kernel(const float* __restrict__ Q, _Float16* __restrict__ QT,
                              _Float16* __restrict__ Qh) {
    __shared__ float tile[32][33];
    int b  = blockIdx.z;
    int j0 = blockIdx.x * 32;
    int d0 = blockIdx.y * 32;
    int tx = threadIdx.x;
    for (int yy = threadIdx.y; yy < 32; yy += 8) {
        float v = Q[((size_t)b * QL_ + j0 + yy) * D_ + d0 + tx];
        tile[yy][tx] = v;
        Qh[((size_t)b * QL_ + j0 + yy) * D_ + d0 + tx] = (_Float16)v;
    }
    __syncthreads();
    for (int yy = threadIdx.y; yy < 32; yy += 8)
        QT[((size_t)b * D_ + d0 + yy) * QL_ + j0 + tx] = (_Float16)tile[tx][yy];
}

// ---- fused: S-GEMM (128 x 256) + cw1 + row softmax -> S1h + col partial stats ----
__global__ __launch_bounds__(512, 2) void fused_s_kernel(
    const float* __restrict__ C, const _Float16* __restrict__ Qh,
    const float* __restrict__ w, const float* __restrict__ qw2g,
    const int* __restrict__ c_mask, const int* __restrict__ q_mask,
    _Float16* __restrict__ S1h, float* __restrict__ pmg,
    float* __restrict__ psg, float* __restrict__ pumg) {
    __shared__ __align__(16) _Float16 As[128 * 64];
    __shared__ __align__(16) _Float16 Bs[256 * 64];
    __shared__ float w1s[D_], w3s[D_];
    __shared__ float cw1s[128];
    __shared__ float rowredM[512], rowredS[512];
    __shared__ int   cms[128], qms[256];

    int t = threadIdx.x;
    int slice = blockIdx.x;      // 0..7
    int b = blockIdx.y;
    int i0 = slice * 128;
    int wave = t >> 6, lane = t & 63, lrow = lane & 15, lk = lane >> 4;
    int wr = wave >> 2, wc = wave & 3;
    int jw = wc * 64;

    for (int k = t; k < D_; k += 512) { w1s[k] = w[k]; w3s[k] = w[2 * D_ + k]; }
    if (t < 128) cms[t] = c_mask[b * CL_ + i0 + t];
    if (t < 256) qms[t] = q_mask[b * QL_ + t];

    const float* Cbase = C + ((size_t)b * CL_ + i0) * D_;
    const _Float16* Qbase = Qh + (size_t)b * QL_ * D_;

    f32x4 acc[4][4] = {};
    float cwp0 = 0.f, cwp1 = 0.f;
    int arow0 = t >> 3, arow1 = 64 + (t >> 3);
    int asc = t & 7;

    for (int k0 = 0; k0 < D_; k0 += 64) {
        __syncthreads();
        {
            int kk0 = k0 + asc * 8;
            float4 w30 = *(const float4*)(&w3s[kk0]);
            float4 w31 = *(const float4*)(&w3s[kk0 + 4]);
            float4 w10 = *(const float4*)(&w1s[kk0]);
            float4 w11 = *(const float4*)(&w1s[kk0 + 4]);
            const float* src0 = Cbase + (size_t)arow0 * D_ + kk0;
            float4 a0 = *(const float4*)src0;
            float4 a1 = *(const float4*)(src0 + 4);
            f16x8 ah;
            ah[0] = (_Float16)(a0.x * w30.x); ah[1] = (_Float16)(a0.y * w30.y);
            ah[2] = (_Float16)(a0.z * w30.z); ah[3] = (_Float16)(a0.w * w30.w);
            ah[4] = (_Float16)(a1.x * w31.x); ah[5] = (_Float16)(a1.y * w31.y);
            ah[6] = (_Float16)(a1.z * w31.z); ah[7] = (_Float16)(a1.w * w31.w);
            cwp0 += a0.x * w10.x + a0.y * w10.y + a0.z * w10.z + a0.w * w10.w
                  + a1.x * w11.x + a1.y * w11.y + a1.z * w11.z + a1.w * w11.w;
            *(f16x8*)&As[arow0 * 64 + ((asc ^ (arow0 & 7)) * 8)] = ah;
            const float* src1 = Cbase + (size_t)arow1 * D_ + kk0;
            float4 b0 = *(const float4*)src1;
            float4 b1 = *(const float4*)(src1 + 4);
            f16x8 bh;
            bh[0] = (_Float16)(b0.x * w30.x); bh[1] = (_Float16)(b0.y * w30.y);
            bh[2] = (_Float16)(b0.z * w30.z); bh[3] = (_Float16)(b0.w * w30.w);
            bh[4] = (_Float16)(b1.x * w31.x); bh[5] = (_Float16)(b1.y * w31.y);
            bh[6] = (_Float16)(b1.z * w31.z); bh[7] = (_Float16)(b1.w * w31.w);
            cwp1 += b0.x * w10.x + b0.y * w10.y + b0.z * w10.z + b0.w * w10.w
                  + b1.x * w11.x + b1.y * w11.y + b1.z * w11.z + b1.w * w11.w;
            *(f16x8*)&As[arow1 * 64 + ((asc ^ (arow1 & 7)) * 8)] = bh;
        }
#pragma unroll
        for (int sb = 0; sb < 4; ++sb) {
            int row = sb * 64 + (t >> 3);
            f16x8 bh = *(const f16x8*)(Qbase + (size_t)row * D_ + k0 + asc * 8);
            *(f16x8*)&Bs[row * 64 + ((asc ^ (row & 7)) * 8)] = bh;
        }
        __syncthreads();
#pragma unroll
        for (int kk = 0; kk < 2; ++kk) {
            int slot = kk * 4 + lk;
            int swa = (slot ^ (lrow & 7)) * 8;
            f16x8 af[4];
#pragma unroll
            for (int m = 0; m < 4; ++m)
                af[m] = *(const f16x8*)&As[(wr * 64 + m * 16 + lrow) * 64 + swa];
#pragma unroll
            for (int n = 0; n < 4; ++n) {
                int rb = jw + n * 16 + lrow;
                f16x8 bf = *(const f16x8*)&Bs[rb * 64 + swa];
#pragma unroll
                for (int m = 0; m < 4; ++m)
                    acc[m][n] = __builtin_amdgcn_mfma_f32_16x16x32_f16(af[m], bf, acc[m][n], 0, 0, 0);
            }
        }
    }

    // ---- cw1 reduction: 8 threads (t&7) share each row ----
    cwp0 += __shfl_xor(cwp0, 1, 64); cwp0 += __shfl_xor(cwp0, 2, 64); cwp0 += __shfl_xor(cwp0, 4, 64);
    cwp1 += __shfl_xor(cwp1, 1, 64); cwp1 += __shfl_xor(cwp1, 2, 64); cwp1 += __shfl_xor(cwp1, 4, 64);
    if ((t & 7) == 0) { cw1s[arow0] = cwp0; cw1s[arow1] = cwp1; }
    __syncthreads();

    // ---- S = clip(acc + cw1 + qw2) in-register ----
    float qwv[4]; int qmv[4];
#pragma unroll
    for (int n = 0; n < 4; ++n) {
        int j = jw + n * 16 + lrow;
        qwv[n] = qw2g[b * QL_ + j];
        qmv[n] = qms[j];
    }
#pragma unroll
    for (int m = 0; m < 4; ++m) {
#pragma unroll
        for (int r = 0; r < 4; ++r) {
            float cw = cw1s[wr * 64 + m * 16 + lk * 4 + r];
#pragma unroll
            for (int n = 0; n < 4; ++n) {
                float v = acc[m][n][r] + cw + qwv[n];
                acc[m][n][r] = fminf(15.f, fmaxf(-15.f, v));
            }
        }
    }

    // ---- column partial stats (per j over this wave's 64 rows; slice16 = slice*2+wr) ----
    {
        float pmv[4], psv[4], pumv[4];
#pragma unroll
        for (int n = 0; n < 4; ++n) {
            float pmax = -1e30f, umax = -1e30f;
#pragma unroll
            for (int m = 0; m < 4; ++m)
#pragma unroll
                for (int r = 0; r < 4; ++r) {
                    int cm = cms[wr * 64 + m * 16 + lk * 4 + r];
                    float v = acc[m][n][r];
                    pmax = fmaxf(pmax, cm ? v : 0.0f);
                    umax = fmaxf(umax, cm ? v : -1e30f);
                }
            float s = 0.f;
#pragma unroll
            for (int m = 0; m < 4; ++m)
#pragma unroll
                for (int r = 0; r < 4; ++r) {
                    int cm = cms[wr * 64 + m * 16 + lk * 4 + r];
                    s += cm ? __expf(acc[m][n][r] - pmax) : 0.0f;
                }
            pmv[n] = pmax; psv[n] = s; pumv[n] = umax;
        }
#pragma unroll
        for (int off = 16; off <= 32; off <<= 1) {
#pragma unroll
            for (int n = 0; n < 4; ++n) {
                float om = __shfl_xor(pmv[n], off, 64);
                float os = __shfl_xor(psv[n], off, 64);
                float ou = __shfl_xor(pumv[n], off, 64);
                float nm = fmaxf(pmv[n], om);
                psv[n] = psv[n] * __expf(pmv[n] - nm) + os * __expf(om - nm);
                pmv[n] = nm;
                pumv[n] = fmaxf(pumv[n], ou);
            }
        }
        if (lk == 0) {
#pragma unroll
            for (int n = 0; n < 4; ++n) {
                int idx = (b * 16 + slice * 2 + wr) * QL_ + jw + n * 16 + lrow;
                pmg[idx] = pmv[n]; psg[idx] = psv[n]; pumg[idx] = pumv[n];
            }
        }
    }

    // ---- row softmax (masked by q_mask), combine across the 4 wc-waves of each wr ----
    float Mv[4][4];
#pragma unroll
    for (int m = 0; m < 4; ++m)
#pragma unroll
        for (int r = 0; r < 4; ++r) {
            float lm = qmv[0] ? acc[m][0][r] : 0.0f;
#pragma unroll
            for (int n = 1; n < 4; ++n) lm = fmaxf(lm, qmv[n] ? acc[m][n][r] : 0.0f);
            lm = fmaxf(lm, __shfl_xor(lm, 1, 64));
            lm = fmaxf(lm, __shfl_xor(lm, 2, 64));
            lm = fmaxf(lm, __shfl_xor(lm, 4, 64));
            lm = fmaxf(lm, __shfl_xor(lm, 8, 64));
            Mv[m][r] = lm;
        }
    if (lrow == 0) {
#pragma unroll
        for (int m = 0; m < 4; ++m)
#pragma unroll
            for (int r = 0; r < 4; ++r)
                rowredM[wave * 64 + m * 16 + lk * 4 + r] = Mv[m][r];
    }
    __syncthreads();
#pragma unroll
    for (int m = 0; m < 4; ++m)
#pragma unroll
        for (int r = 0; r < 4; ++r) {
            int row = wr * 256 + m * 16 + lk * 4 + r;
            Mv[m][r] = fmaxf(fmaxf(rowredM[row], rowredM[64 + row]),
                             fmaxf(rowredM[128 + row], rowredM[192 + row]));
        }
    float inv_[4][4];
#pragma unroll
    for (int m = 0; m < 4; ++m)
#pragma unroll
        for (int r = 0; r < 4; ++r) {
            float ls = 0.f;
#pragma unroll
            for (int n = 0; n < 4; ++n) {
                float e = qmv[n] ? __expf(acc[m][n][r] - Mv[m][r]) : 0.0f;
                acc[m][n][r] = e;
                ls += e;
            }
            ls += __shfl_xor(ls, 1, 64);
            ls += __shfl_xor(ls, 2, 64);
            ls += __shfl_xor(ls, 4, 64);
            ls += __shfl_xor(ls, 8, 64);
            if (lrow == 0) rowredS[wave * 64 + m * 16 + lk * 4 + r] = ls;
        }
    __syncthreads();
#pragma unroll
    for (int m = 0; m < 4; ++m)
#pragma unroll
        for (int r = 0; r < 4; ++r) {
            int row = wr * 256 + m * 16 + lk * 4 + r;
            float sum = rowredS[row] + rowredS[64 + row] + rowredS[128 + row] + rowredS[192 + row];
            inv_[m][r] = 1.0f / (sum + 1e-6f);
        }

    // ---- write S1 (f16): two 64-row passes through Bs (swizzled), coalesced writeback ----
    char* Bs2 = (char*)Bs;
#pragma unroll
    for (int p = 0; p < 2; ++p) {
        __syncthreads();
        if (wr == p) {
#pragma unroll
            for (int m = 0; m < 4; ++m)
#pragma unroll
                for (int n = 0; n < 4; ++n)
#pragma unroll
                    for (int r = 0; r < 4; ++r) {
                        int il = m * 16 + lk * 4 + r;
                        int jj = jw + n * 16 + lrow;
                        int byte = il * 512 + (((jj >> 3) ^ (il & 7)) * 16) + (jj & 7) * 2;
                        *(_Float16*)(Bs2 + byte) = (_Float16)(acc[m][n][r] * inv_[m][r]);
                    }
        }
        __syncthreads();
#pragma unroll
        for (int sb = 0; sb < 4; ++sb) {
            int row = sb * 16 + (t >> 5);
            int c = t & 31;
            uint4 v = *(uint4*)(Bs2 + row * 512 + ((c ^ (row & 7)) * 16));
            *(uint4*)(S1h + ((size_t)(b * CL_ + i0 + p * 64 + row)) * QL_ + c * 8) = v;
        }
    }
}

// ---------------- column combine (16 slices) -> s2max -> Bmat ----------------
__global__ void combine_bmat_kernel(const float* __restrict__ pm, const float* __restrict__ ps,
                                    const float* __restrict__ pum, const _Float16* __restrict__ Qh,
                                    float* __restrict__ bmat) {
    __shared__ float sm[QL_];
    int b = blockIdx.x;
    int t = threadIdx.x;
    {
        float m = -1e30f, s = 0.f, um = -1e30f;
        for (int k = 0; k < 16; ++k) {
            int idx = (b * 16 + k) * QL_ + t;
            float mk = pm[idx], sk = ps[idx], umk = pum[idx];
            float nm = fmaxf(m, mk);
            s = s * __expf(m - nm) + sk * __expf(mk - nm);
            m = nm;
            um = fmaxf(um, umk);
        }
        sm[t] = (um < -1e29f) ? 0.0f : __expf(um - m) / (s + 1e-6f);
    }
    __syncthreads();
#pragma unroll
    for (int c = 0; c < 3; ++c) {
        int d = c * 256 + t;
        const _Float16* qb = Qh + (size_t)b * QL_ * D_ + d;
        float s = 0.f;
        for (int j = 0; j < QL_; ++j) s += sm[j] * (float)qb[(size_t)j * D_];
        bmat[b * D_ + d] = s;
    }
}

// ---------------- A-GEMM (S1 @ Q), 128x128 tile, fused 4-segment epilogue ----------------
__global__ __launch_bounds__(512) void agemm_out_kernel(
    const _Float16* __restrict__ S1h, const _Float16* __restrict__ QTh,
    const float* __restrict__ C, const float* __restrict__ bmat, float* __restrict__ out) {
    __shared__ __align__(16) _Float16 As[128 * 64];
    __shared__ __align__(16) _Float16 Bs[128 * 64];
    int t  = threadIdx.x;
    int b  = blockIdx.z;
    int d0 = blockIdx.x * 128;
    int i0 = blockIdx.y * 128;
    const _Float16* Sbase = S1h + ((size_t)b * CL_ + i0) * QL_;
    const _Float16* Qbase = QTh + ((size_t)b * D_ + d0) * QL_;
    int wave = t >> 6, lane = t & 63, lrow = lane & 15, lk = lane >> 4;
    int wr = wave >> 1, wc = wave & 1;
    f32x4 acc[2][4] = {};
    int srow = t >> 3, sc = t & 7;
    for (int k0 = 0; k0 < QL_; k0 += 64) {
        __syncthreads();
#pragma unroll
        for (int s2 = 0; s2 < 2; ++s2) {
            int row = s2 * 64 + srow;
            int sw = (sc ^ (row & 7)) * 8;
            f16x8 av = *(const f16x8*)(Sbase + (size_t)row * QL_ + k0 + sc * 8);
            f16x8 bv = *(const f16x8*)(Qbase + (size_t)row * QL_ + k0 + sc * 8);
            *(f16x8*)&As[row * 64 + sw] = av;
            *(f16x8*)&Bs[row * 64 + sw] = bv;
        }
        __syncthreads();
#pragma unroll
        for (int kk = 0; kk < 2; ++kk) {
            int slot = kk * 4 + lk;
            int swa = (slot ^ (lrow & 7)) * 8;
            f16x8 af[2];
#pragma unroll
            for (int m = 0; m < 2; ++m)
                af[m] = *(const f16x8*)&As[(wr * 32 + m * 16 + lrow) * 64 + swa];
#pragma unroll
            for (int n = 0; n < 4; ++n) {
                f16x8 bf = *(const f16x8*)&Bs[(wc * 64 + n * 16 + lrow) * 64 + swa];
#pragma unroll
                for (int m = 0; m < 2; ++m)
                    acc[m][n] = __builtin_amdgcn_mfma_f32_16x16x32_f16(af[m], bf, acc[m][n], 0, 0, 0);
            }
        }
    }
#pragma unroll
    for (int n = 0; n < 4; ++n) {
        int d = d0 + wc * 64 + n * 16 + lrow;
        float bm = bmat[b * D_ + d];
#pragma unroll
        for (int m = 0; m < 2; ++m)
#pragma unroll
            for (int r = 0; r < 4; ++r) {
                int i = i0 + wr * 32 + m * 16 + lk * 4 + r;
                float a = acc[m][n][r];
                float c = C[((size_t)b * CL_ + i) * D_ + d];
                size_t ob = ((size_t)b * CL_ + i) * (size_t)(4 * D_);
                __builtin_nontemporal_store(c,      &out[ob + d]);
                __builtin_nontemporal_store(a,      &out[ob + D_ + d]);
                __builtin_nontemporal_store(c * a,  &out[ob + 2 * D_ + d]);
                __builtin_nontemporal_store(c * bm, &out[ob + 3 * D_ + d]);
            }
    }
}

extern "C" void kernel_launch(void* const* d_in, const int* in_sizes, int n_in,
                              void* d_out, int out_size, void* d_ws, size_t ws_size,
                              hipStream_t stream) {
    const float* C      = (const float*)d_in[0];
    const float* Q      = (const float*)d_in[1];
    const float* w      = (const float*)d_in[2];
    const int*   c_mask = (const int*)d_in[3];
    const int*   q_mask = (const int*)d_in[4];
    float* out = (float*)d_out;
    char* ws = (char*)d_ws;

    // workspace layout (bytes)
    _Float16* S1h   = (_Float16*)(ws);                      // 16,777,216
    _Float16* QTh   = (_Float16*)(ws + 16777216);           // 12,582,912
    _Float16* Qh    = (_Float16*)(ws + 29360128);           // 12,582,912
    float*    qw2   = (float*)(ws + 41943040);              //     32,768
    float*    pm    = (float*)(ws + 41975808);              //    524,288
    float*    ps    = (float*)(ws + 42500096);              //    524,288
    float*    pum   = (float*)(ws + 43024384);              //    524,288
    float*    s2max = (float*)(ws + 43548672);              //     32,768 (unused)
    float*    bmat  = (float*)(ws + 43581440);              //     98,304
    (void)s2max;

    rowdot_kernel<<<dim3((B_ * QL_) / 4), 256, 0, stream>>>(Q, w + D_, qw2);
    prep_q_kernel<<<dim3(QL_ / 32, D_ / 32, B_), dim3(32, 8), 0, stream>>>(Q, QTh, Qh);
    fused_s_kernel<<<dim3(CL_ / 128, B_), 512, 0, stream>>>(C, Qh, w, qw2, c_mask, q_mask,
                                                            S1h, pm, ps, pum);
    combine_bmat_kernel<<<dim3(B_), 256, 0, stream>>>(pm, ps, pum, Qh, bmat);
    agemm_out_kernel<<<dim3(D_ / 128, CL_ / 128, B_), 512, 0, stream>>>(S1h, QTh, C, bmat, out);
}